// Round 9
// baseline (7318.657 us; speedup 1.0000x reference)
//
#include <hip/hip_runtime.h>
#include <hip/hip_bf16.h>

// ---------------------------------------------------------------------------
// UnifiedModelRNN: B=256,S=512,I=64,H=256. 16 blocks x 512 threads (8 waves,
// 2/SIMD); block g owns batch rows [16g,16g+16). No grid sync.
// R9 (= R8 + deeper DMA ring): gate weights streamed via global_load_lds into
// a per-wave-private 4-slot LDS ring (4KB chunks = 4 frags, 3 chunks in
// flight). Counted s_waitcnt vmcnt(8) per chunk (never 0); lgkm-only barriers
// so DMA rides across phases. pit/time head weights in registers (frees the
// 64KB LDS the deeper ring needs); ar weights register-resident.
// Chunk order c=0..19 over kts [2,2,3,3,4,4,5,5,6,6,7,7,8,8,9,9,0,0,1,1],
// half=c&1, slot=c&3; consume C(c) -> issue C(c+3).
// ---------------------------------------------------------------------------

typedef float f32x4 __attribute__((ext_vector_type(4)));
typedef short s16x8 __attribute__((ext_vector_type(8)));

#define S_LEN 512
#define I_DIM 64
#define NT    512

#define WS_GF    0        // gates: 640 frags x 512 elems, f = (wave*8+qm)*10+kt
#define WS_PF    327680   // pit_w1: 32 frags
#define WS_TF    344064   // time_w1[:, :256]: 32 frags
#define WS_AXF   360448   // ar_w1[:, 2:66]: 8 frags
#define WS_A2F   364544   // ar_w2: 8 frags
#define WS_TOTAL 368640

#define OUT_PIT  0
#define OUT_TIME 131072
#define OUT_AR   262144

#define ALD 328
#define XLD 72

__device__ __forceinline__ float sigf(float x) {
  return 1.0f / (1.0f + __expf(-x));
}
__device__ __forceinline__ float tanh_fast(float x) {
  float c = fminf(fmaxf(x, -15.0f), 15.0f);
  float e = __expf(2.0f * c);
  return (e - 1.0f) / (e + 1.0f);
}
__device__ __forceinline__ unsigned short f2bf(float f) {
  __hip_bfloat16 h = __float2bfloat16(f);
  return *reinterpret_cast<unsigned short*>(&h);
}
// LDS-only barrier: does NOT drain vmcnt -> DMA stays in flight.
__device__ __forceinline__ void sync_lds() {
  asm volatile("s_waitcnt lgkmcnt(0)" ::: "memory");
  __builtin_amdgcn_s_barrier();
  asm volatile("" ::: "memory");
}
// 16B/lane global->LDS DMA. gsrc per-lane; ldst wave-uniform base (+lane*16).
__device__ __forceinline__ void gld16(const unsigned short* g, unsigned short* l) {
  __builtin_amdgcn_global_load_lds(
      (const __attribute__((address_space(1))) unsigned int*)g,
      (__attribute__((address_space(3))) unsigned int*)l, 16, 0, 0);
}

__global__ void prep_kernel(const float* __restrict__ w_ih,
                            const float* __restrict__ w_hh,
                            const float* __restrict__ pit_w1,
                            const float* __restrict__ time_w1,
                            const float* __restrict__ ar_w1,
                            const float* __restrict__ ar_w2,
                            unsigned short* __restrict__ ws) {
  int idx = blockIdx.x * 256 + threadIdx.x;
  if (idx >= WS_TOTAL) return;
  int lane = (idx >> 3) & 63;
  int e    = idx & 7;
  int lrow = lane & 15, lgrp = lane >> 4;
  float v;
  if (idx < WS_PF) {
    int f = idx >> 9;                 // 0..639
    int w = f / 80, r = f - w * 80;
    int qm = r / 10, kt = r - qm * 10;
    int q = qm >> 1, m = qm & 1;
    int row = q * 256 + w * 32 + m * 16 + lrow;
    int col = kt * 32 + lgrp * 8 + e;
    v = (col < I_DIM) ? w_ih[row * I_DIM + col] : w_hh[row * 256 + col - I_DIM];
  } else if (idx < WS_TF) {
    int f = (idx - WS_PF) >> 9;       // 0..31
    int wv = f >> 3, kt = f & 7;
    v = pit_w1[(wv * 16 + lrow) * 256 + kt * 32 + lgrp * 8 + e];
  } else if (idx < WS_AXF) {
    int f = (idx - WS_TF) >> 9;
    int wv = f >> 3, kt = f & 7;
    v = time_w1[(wv * 16 + lrow) * 257 + kt * 32 + lgrp * 8 + e];
  } else if (idx < WS_A2F) {
    int f = (idx - WS_AXF) >> 9;      // 0..7
    int wv = f >> 1, kt = f & 1;
    v = ar_w1[(wv * 16 + lrow) * 66 + 2 + kt * 32 + lgrp * 8 + e];
  } else {
    int f = (idx - WS_A2F) >> 9;
    int wv = f >> 1, kt = f & 1;
    v = ar_w2[(wv * 16 + lrow) * 64 + kt * 32 + lgrp * 8 + e];
  }
  ws[idx] = f2bf(v);
}

#define AFRAG(kt) (*(const s16x8*)&A_lds[lrow][(kt) * 32 + 8 * lgrp])
#define GFRAG(kt, qm) \
  (*(const s16x8*)&ws[((wave * 8 + (qm)) * 10 + (kt)) * 512 + lane * 8])

// DMA chunk (kt, half) -> stg[wave][slot]: 4 frags (qm = half*4+j), 4KB.
#define DMA_CHUNK(kt, half, slot)                                              \
  do {                                                                         \
    _Pragma("unroll")                                                          \
    for (int j = 0; j < 4; ++j) {                                              \
      const unsigned short* gp =                                               \
          &ws[((wave * 8 + (half) * 4 + j) * 10 + (kt)) * 512 + lane * 8];     \
      gld16(gp, &stg[wave][slot][j * 512]);                                    \
    }                                                                          \
  } while (0)

// Consume chunk in slot `cslot` (vmcnt(8): this chunk landed, next 2 still in
// flight), then issue chunk c+3 = (nkt,nhalf) into slot nslot.
#define GSTEP(af, chalf, cslot, nkt, nhalf, nslot)                             \
  do {                                                                         \
    asm volatile("s_waitcnt vmcnt(8)" ::: "memory");                           \
    _Pragma("unroll")                                                          \
    for (int j = 0; j < 4; ++j) {                                              \
      s16x8 b = *(const s16x8*)&stg[wave][cslot][j * 512 + lane * 8];          \
      acc2[(chalf) * 4 + j] = __builtin_amdgcn_mfma_f32_16x16x32_bf16(         \
          (af), b, acc2[(chalf) * 4 + j], 0, 0, 0);                            \
    }                                                                          \
    asm volatile("s_waitcnt lgkmcnt(0)" ::: "memory");                         \
    DMA_CHUNK(nkt, nhalf, nslot);                                              \
  } while (0)

__global__ __launch_bounds__(NT, 2)
__attribute__((amdgpu_waves_per_eu(2, 2)))
void rnn_kernel(
    const float* __restrict__ x,
    const float* __restrict__ b_ih, const float* __restrict__ b_hh,
    const float* __restrict__ pit_b1, const float* __restrict__ pit_w2,
    const float* __restrict__ pit_b2,
    const float* __restrict__ time_w1, const float* __restrict__ time_b1,
    const float* __restrict__ time_w2, const float* __restrict__ time_b2,
    const float* __restrict__ ar_w1, const float* __restrict__ ar_b1,
    const float* __restrict__ ar_b2,
    const unsigned short* __restrict__ ws,
    float* __restrict__ out)
{
  __shared__ __align__(16) unsigned short A_lds[16][ALD];    // [x(64) | h(256)]
  __shared__ __align__(16) unsigned short xo_lds[16][XLD];   // x_orig[t]
  __shared__ __align__(16) unsigned short ar1_lds[16][XLD];  // relu(ar1)
  __shared__ __align__(16) unsigned short stg[8][4][2048];   // DMA ring (128 KB)
  __shared__ float pitp[4][16];
  __shared__ float timep[4][16];

  const int tid  = threadIdx.x;
  const int wave = tid >> 6;
  const int lane = tid & 63;
  const int lrow = lane & 15;
  const int lgrp = lane >> 4;
  const int b0   = blockIdx.x * 16;
  const int hcol = (wave & 3) * 16 + lrow;

  for (int i = tid; i < 16 * ALD; i += NT) (&A_lds[0][0])[i] = 0;

  // ---- role constants ----
  float gbias[8];
#pragma unroll
  for (int qm = 0; qm < 8; ++qm) {
    int g = (qm >> 1) * 256 + wave * 32 + (qm & 1) * 16 + lrow;
    gbias[qm] = b_ih[g] + b_hh[g];
  }
  // pit (waves 0-3) / time (waves 4-7) first-layer weights in registers.
  s16x8 hw1[8];
  {
    const unsigned short* hbase =
        ws + ((wave < 4) ? WS_PF : WS_TF) + (wave & 3) * 8 * 512;
#pragma unroll
    for (int kt = 0; kt < 8; ++kt)
      hw1[kt] = *(const s16x8*)&hbase[kt * 512 + lane * 8];
  }
  s16x8 arw[2];
  float pb1v = 0, pw2v = 0, tb1v = 0, tw2v = 0, twlv = 0;
  float ab1v = 0, arpv = 0, artv = 0, ab2v = 0;
  if (wave < 4) {
    arw[0] = *(const s16x8*)&ws[WS_AXF + ((wave & 3) * 2 + 0) * 512 + lane * 8];
    arw[1] = *(const s16x8*)&ws[WS_AXF + ((wave & 3) * 2 + 1) * 512 + lane * 8];
    pb1v = pit_b1[hcol]; pw2v = pit_w2[hcol];
    ab1v = ar_b1[hcol];  arpv = ar_w1[hcol * 66]; artv = ar_w1[hcol * 66 + 1];
  } else {
    arw[0] = *(const s16x8*)&ws[WS_A2F + ((wave & 3) * 2 + 0) * 512 + lane * 8];
    arw[1] = *(const s16x8*)&ws[WS_A2F + ((wave & 3) * 2 + 1) * 512 + lane * 8];
    tb1v = time_b1[hcol]; tw2v = time_w2[hcol];
    twlv = time_w1[hcol * 257 + 256]; ab2v = ar_b2[hcol];
  }
  const float pb2 = pit_b2[0], tb2 = time_b2[0];

  // ---- stage x[:,0,:], write ar_out[:,0,:] ----
  const int srow = tid >> 5;
  const int sc2  = (tid & 31) * 2;
  const size_t xbase = (size_t)(b0 + srow) * S_LEN * I_DIM + sc2;
  float2 xpre = *reinterpret_cast<const float2*>(&x[xbase]);
  __syncthreads();
  A_lds[srow][sc2]     = f2bf(xpre.x);
  A_lds[srow][sc2 + 1] = f2bf(xpre.y);
  *reinterpret_cast<float2*>(&out[OUT_AR + xbase]) = xpre;

  float cst[2][4];
#pragma unroll
  for (int m = 0; m < 2; ++m)
#pragma unroll
    for (int r = 0; r < 4; ++r) cst[m][r] = 0.0f;
  __syncthreads();

  // ---- prologue: gates(0) = bias + x0-part (h=0); direct register loads ----
  f32x4 acc2[8];
#pragma unroll
  for (int qm = 0; qm < 8; ++qm) {
    f32x4 tv; tv[0] = tv[1] = tv[2] = tv[3] = gbias[qm];
    acc2[qm] = tv;
  }
#pragma unroll
  for (int kt = 0; kt < 2; ++kt) {
    s16x8 aK = AFRAG(kt);
#pragma unroll
    for (int qm = 0; qm < 8; ++qm)
      acc2[qm] = __builtin_amdgcn_mfma_f32_16x16x32_bf16(aK, GFRAG(kt, qm), acc2[qm], 0, 0, 0);
  }
  // prime the ring: c0=(kt2,h0,s0), c1=(kt2,h1,s1), c2=(kt3,h0,s2)
  DMA_CHUNK(2, 0, 0);
  DMA_CHUNK(2, 1, 1);
  DMA_CHUNK(3, 0, 2);

  // =========================== time loop ===========================
  for (int t = 0; t < S_LEN; ++t) {
    // ---- P0: xo stage, x prefetch, LSTM -> h ----
    xo_lds[srow][sc2]     = f2bf(xpre.x);
    xo_lds[srow][sc2 + 1] = f2bf(xpre.y);
    if (t + 1 < S_LEN)
      xpre = *reinterpret_cast<const float2*>(&x[xbase + (size_t)(t + 1) * I_DIM]);

#pragma unroll
    for (int m = 0; m < 2; ++m)
#pragma unroll
      for (int r = 0; r < 4; ++r) {
        float ig = sigf(acc2[0 + m][r]);
        float fg = sigf(acc2[2 + m][r]);
        float gg = tanh_fast(acc2[4 + m][r]);
        float og = sigf(acc2[6 + m][r]);
        float c  = fg * cst[m][r] + ig * gg;
        cst[m][r] = c;
        A_lds[lgrp * 4 + r][64 + wave * 32 + m * 16 + lrow] = f2bf(og * tanh_fast(c));
      }
#pragma unroll
    for (int qm = 0; qm < 8; ++qm) {
      f32x4 tv; tv[0] = tv[1] = tv[2] = tv[3] = gbias[qm];
      acc2[qm] = tv;
    }
    sync_lds();  // barrier A: h + xo ready

    // ---- P1: heads main; pit reduce; gate chunks c0..c7 (kt2-5) ----
    s16x8 hfr[8];
#pragma unroll
    for (int k = 0; k < 8; ++k)
      hfr[k] = *(const s16x8*)&A_lds[lrow][64 + k * 32 + 8 * lgrp];

    f32x4 hacc;
    {
      float hb = (wave < 4) ? pb1v : tb1v;
      hacc[0] = hacc[1] = hacc[2] = hacc[3] = hb;
#pragma unroll
      for (int kt = 0; kt < 8; ++kt)
        hacc = __builtin_amdgcn_mfma_f32_16x16x32_bf16(hfr[kt], hw1[kt], hacc, 0, 0, 0);
    }
    if (wave < 4) {  // pit partial reduce
      float v[4];
#pragma unroll
      for (int r = 0; r < 4; ++r) v[r] = fmaxf(hacc[r], 0.0f) * pw2v;
#pragma unroll
      for (int off = 1; off < 16; off <<= 1)
#pragma unroll
        for (int r = 0; r < 4; ++r) v[r] += __shfl_xor(v[r], off);
      if (lrow == 0) {
#pragma unroll
        for (int r = 0; r < 4; ++r) pitp[wave][lgrp * 4 + r] = v[r];
      }
    }
    GSTEP(hfr[0], 0, 0, 3, 1, 3);  // c0: kt2h0 -> issue c3 (kt3h1)
    GSTEP(hfr[0], 1, 1, 4, 0, 0);  // c1: kt2h1 -> c4 (kt4h0)
    GSTEP(hfr[1], 0, 2, 4, 1, 1);  // c2: kt3h0 -> c5
    GSTEP(hfr[1], 1, 3, 5, 0, 2);  // c3: kt3h1 -> c6
    GSTEP(hfr[2], 0, 0, 5, 1, 3);  // c4: kt4h0 -> c7
    GSTEP(hfr[2], 1, 1, 6, 0, 0);  // c5: kt4h1 -> c8
    GSTEP(hfr[3], 0, 2, 6, 1, 1);  // c6: kt5h0 -> c9
    GSTEP(hfr[3], 1, 3, 7, 0, 2);  // c7: kt5h1 -> c10
    sync_lds();  // barrier 1: pit partials ready

    // ---- P2: pv; time finish / ar1-x; pit out; chunks c8..c11 (kt6,7) ----
    float pv[4];
#pragma unroll
    for (int r = 0; r < 4; ++r) {
      int row = lgrp * 4 + r;
      pv[r] = pitp[0][row] + pitp[1][row] + pitp[2][row] + pitp[3][row] + pb2;
    }
    f32x4 aracc;
    if (wave < 4) {
      aracc[0] = aracc[1] = aracc[2] = aracc[3] = ab1v;
#pragma unroll
      for (int kt = 0; kt < 2; ++kt) {
        s16x8 aX = *(const s16x8*)&xo_lds[lrow][kt * 32 + 8 * lgrp];
        aracc = __builtin_amdgcn_mfma_f32_16x16x32_bf16(aX, arw[kt], aracc, 0, 0, 0);
      }
      if (wave == 0 && lane < 16) {
        float pvs = pitp[0][lane] + pitp[1][lane] + pitp[2][lane] + pitp[3][lane] + pb2;
        out[OUT_PIT + (size_t)(b0 + lane) * S_LEN + t] = pvs;
      }
    } else {
      float v[4];
#pragma unroll
      for (int r = 0; r < 4; ++r)
        v[r] = fmaxf(hacc[r] + pv[r] * twlv, 0.0f) * tw2v;
#pragma unroll
      for (int off = 1; off < 16; off <<= 1)
#pragma unroll
        for (int r = 0; r < 4; ++r) v[r] += __shfl_xor(v[r], off);
      if (lrow == 0) {
#pragma unroll
        for (int r = 0; r < 4; ++r) timep[wave & 3][lgrp * 4 + r] = v[r];
      }
    }
    GSTEP(hfr[4], 0, 0, 7, 1, 3);  // c8:  kt6h0 -> c11
    GSTEP(hfr[4], 1, 1, 8, 0, 0);  // c9:  kt6h1 -> c12
    GSTEP(hfr[5], 0, 2, 8, 1, 1);  // c10: kt7h0 -> c13
    GSTEP(hfr[5], 1, 3, 9, 0, 2);  // c11: kt7h1 -> c14
    sync_lds();  // barrier 2: time partials ready

    // ---- P3: tv; ar1 finish; time out; chunks c12..c15 (kt8,9) ----
    float tvv[4];
#pragma unroll
    for (int r = 0; r < 4; ++r) {
      int row = lgrp * 4 + r;
      tvv[r] = timep[0][row] + timep[1][row] + timep[2][row] + timep[3][row] + tb2;
    }
    if (wave < 4) {
#pragma unroll
      for (int r = 0; r < 4; ++r) {
        float a1 = aracc[r] + pv[r] * arpv + tvv[r] * artv;
        ar1_lds[lgrp * 4 + r][hcol] = f2bf(fmaxf(a1, 0.0f));
      }
    } else if (wave == 4 && lane < 16) {
      float tvs = timep[0][lane] + timep[1][lane] + timep[2][lane] + timep[3][lane] + tb2;
      out[OUT_TIME + (size_t)(b0 + lane) * S_LEN + t] = tvs;
    }
    GSTEP(hfr[6], 0, 0, 9, 1, 3);  // c12: kt8h0 -> c15
    GSTEP(hfr[6], 1, 1, 0, 0, 0);  // c13: kt8h1 -> c16 (kt0h0)
    GSTEP(hfr[7], 0, 2, 0, 1, 1);  // c14: kt9h0 -> c17
    GSTEP(hfr[7], 1, 3, 1, 0, 2);  // c15: kt9h1 -> c18
    sync_lds();  // barrier 3: ar1 ready

    // ---- P4: ar2 -> x_{t+1} (waves 4-7) ----
    if (wave >= 4) {
      f32x4 nacc;
      nacc[0] = nacc[1] = nacc[2] = nacc[3] = ab2v;
#pragma unroll
      for (int kt = 0; kt < 2; ++kt) {
        s16x8 aR = *(const s16x8*)&ar1_lds[lrow][kt * 32 + 8 * lgrp];
        nacc = __builtin_amdgcn_mfma_f32_16x16x32_bf16(aR, arw[kt], nacc, 0, 0, 0);
      }
#pragma unroll
      for (int r = 0; r < 4; ++r) {
        int row = lgrp * 4 + r;
        A_lds[row][hcol] = f2bf(nacc[r]);
        if (t < S_LEN - 1)
          out[OUT_AR + (size_t)(b0 + row) * S_LEN * I_DIM + (size_t)(t + 1) * I_DIM + hcol] = nacc[r];
      }
    }
    sync_lds();  // barrier B: x_{t+1} staged

    // ---- P5: gates-x chunks c16..c19 (kt0,1); prime next step's c0..c2 ----
    {
      s16x8 a0 = AFRAG(0);
      GSTEP(a0, 0, 0, 1, 1, 3);    // c16: kt0h0 -> c19 (kt1h1)
      GSTEP(a0, 1, 1, 2, 0, 0);    // c17: kt0h1 -> c0' (next kt2h0)
      s16x8 a1 = AFRAG(1);
      GSTEP(a1, 0, 2, 2, 1, 1);    // c18: kt1h0 -> c1'
      GSTEP(a1, 1, 3, 3, 0, 2);    // c19: kt1h1 -> c2'
    }
  }
}

extern "C" void kernel_launch(void* const* d_in, const int* in_sizes, int n_in,
                              void* d_out, int out_size, void* d_ws, size_t ws_size,
                              hipStream_t stream) {
  const float* x       = (const float*)d_in[0];
  const float* w_ih    = (const float*)d_in[1];
  const float* w_hh    = (const float*)d_in[2];
  const float* b_ih    = (const float*)d_in[3];
  const float* b_hh    = (const float*)d_in[4];
  const float* pit_w1  = (const float*)d_in[5];
  const float* pit_b1  = (const float*)d_in[6];
  const float* pit_w2  = (const float*)d_in[7];
  const float* pit_b2  = (const float*)d_in[8];
  const float* time_w1 = (const float*)d_in[9];
  const float* time_b1 = (const float*)d_in[10];
  const float* time_w2 = (const float*)d_in[11];
  const float* time_b2 = (const float*)d_in[12];
  const float* ar_w1   = (const float*)d_in[13];
  const float* ar_b1   = (const float*)d_in[14];
  const float* ar_w2   = (const float*)d_in[15];
  const float* ar_b2   = (const float*)d_in[16];
  unsigned short* ws   = (unsigned short*)d_ws;
  float* out           = (float*)d_out;

  prep_kernel<<<dim3((WS_TOTAL + 255) / 256), dim3(256), 0, stream>>>(
      w_ih, w_hh, pit_w1, time_w1, ar_w1, ar_w2, ws);
  rnn_kernel<<<dim3(16), dim3(NT), 0, stream>>>(
      x, b_ih, b_hh, pit_b1, pit_w2, pit_b2,
      time_w1, time_b1, time_w2, time_b2,
      ar_w1, ar_b1, ar_b2, ws, out);
}